// Round 2
// baseline (922.870 us; speedup 1.0000x reference)
//
#include <hip/hip_runtime.h>
#include <hip/hip_bf16.h>

// ---------------- CSR build ----------------

__global__ void k_count(const int* __restrict__ dst, int* __restrict__ cnt, int E) {
  int e = blockIdx.x * 256 + threadIdx.x;
  if (e < E) atomicAdd(&cnt[dst[e]], 1);
}

__global__ void k_scan1(const int* __restrict__ cnt, int* __restrict__ bsum, int N) {
  __shared__ int sh[256];
  int t = threadIdx.x;
  int base = blockIdx.x * 1024 + t * 4;
  int s = 0;
  #pragma unroll
  for (int q = 0; q < 4; ++q) { int i = base + q; if (i < N) s += cnt[i]; }
  sh[t] = s; __syncthreads();
  for (int off = 128; off > 0; off >>= 1) {
    if (t < off) sh[t] += sh[t + off];
    __syncthreads();
  }
  if (t == 0) bsum[blockIdx.x] = sh[0];
}

__global__ void k_scan2(const int* __restrict__ bsum, int* __restrict__ boff,
                        int* __restrict__ row_ptr, int NB, int N) {
  __shared__ int sh[128];
  int t = threadIdx.x;
  int v = (t < NB) ? bsum[t] : 0;
  sh[t] = v; __syncthreads();
  for (int off = 1; off < 128; off <<= 1) {
    int y = (t >= off) ? sh[t - off] : 0;
    __syncthreads();
    sh[t] += y;
    __syncthreads();
  }
  if (t < NB) boff[t] = sh[t] - v;
  if (t == 127) row_ptr[N] = sh[127];
}

__global__ void k_scan3(const int* __restrict__ cnt, const int* __restrict__ boff,
                        int* __restrict__ row_ptr, int N) {
  __shared__ int sh[256];
  int t = threadIdx.x;
  int base = blockIdx.x * 1024 + t * 4;
  int c0 = 0, c1 = 0, c2 = 0, c3 = 0;
  if (base + 0 < N) c0 = cnt[base + 0];
  if (base + 1 < N) c1 = cnt[base + 1];
  if (base + 2 < N) c2 = cnt[base + 2];
  if (base + 3 < N) c3 = cnt[base + 3];
  int s = c0 + c1 + c2 + c3;
  sh[t] = s; __syncthreads();
  for (int off = 1; off < 256; off <<= 1) {
    int y = (t >= off) ? sh[t - off] : 0;
    __syncthreads();
    sh[t] += y;
    __syncthreads();
  }
  int run = boff[blockIdx.x] + sh[t] - s;
  if (base + 0 < N) row_ptr[base + 0] = run; run += c0;
  if (base + 1 < N) row_ptr[base + 1] = run; run += c1;
  if (base + 2 < N) row_ptr[base + 2] = run; run += c2;
  if (base + 3 < N) row_ptr[base + 3] = run;
}

__global__ void k_fill(const int* __restrict__ src, const int* __restrict__ dst,
                       int* __restrict__ cursor, int* __restrict__ csr_src, int E) {
  int e = blockIdx.x * 256 + threadIdx.x;
  if (e < E) {
    int pos = atomicAdd(&cursor[dst[e]], 1);
    csr_src[pos] = src[e];
  }
}

// ---------------- aggregation: wave-per-node gather-mean ----------------
// lane k owns feature column k; each edge = one coalesced 256B wave-load.
// ~16 VGPR, no LDS -> high occupancy; 4x unroll keeps many loads in flight.

__global__ __launch_bounds__(256) void k_agg(
    const float* __restrict__ feat, const int* __restrict__ rp,
    const int* __restrict__ csrc, float* __restrict__ aggout, int N)
{
  int lane = threadIdx.x & 63;
  int i = (blockIdx.x * 256 + threadIdx.x) >> 6;   // wave id == node id
  if (i >= N) return;
  int e0 = rp[i], e1 = rp[i + 1];
  float acc = 0.f;
  int e = e0;
  for (; e + 4 <= e1; e += 4) {
    int s0 = csrc[e + 0];
    int s1 = csrc[e + 1];
    int s2 = csrc[e + 2];
    int s3 = csrc[e + 3];
    float v0 = feat[(size_t)s0 * 64 + lane];
    float v1 = feat[(size_t)s1 * 64 + lane];
    float v2 = feat[(size_t)s2 * 64 + lane];
    float v3 = feat[(size_t)s3 * 64 + lane];
    acc += v0; acc += v1; acc += v2; acc += v3;
  }
  for (; e < e1; ++e) acc += feat[(size_t)csrc[e] * 64 + lane];
  int len = e1 - e0;
  float inv = (len > 0) ? (1.f / (float)len) : 1.f;
  aggout[(size_t)i * 64 + lane] = acc * inv;
}

// ---------------- transform: out = relu(f@Ws + agg@Wn + b) ----------------
// Thread-per-node; W^T staged in LDS, read as wave-uniform broadcast float4.
// block=128 -> 782 blocks (3/CU) for better load balance than 391.

__global__ __launch_bounds__(128) void k_xform(
    const float* __restrict__ feat, const float* __restrict__ agg,
    const float* __restrict__ Ws, const float* __restrict__ Wn,
    const float* __restrict__ bias, float* __restrict__ out, int N)
{
  __shared__ float sWsT[64 * 64];
  __shared__ float sWnT[64 * 64];
  __shared__ float sb[64];
  for (int idx = threadIdx.x; idx < 4096; idx += 128) {
    int k = idx >> 6, j = idx & 63;
    sWsT[j * 64 + k] = Ws[idx];
    sWnT[j * 64 + k] = Wn[idx];
  }
  if (threadIdx.x < 64) sb[threadIdx.x] = bias[threadIdx.x];
  __syncthreads();

  int i = blockIdx.x * 128 + threadIdx.x;
  if (i >= N) return;

  const float4* feat4 = (const float4*)feat;
  const float4* agg4  = (const float4*)agg;
  float f[64], nv[64];
  #pragma unroll
  for (int q = 0; q < 16; ++q) {
    float4 v = feat4[(size_t)i * 16 + q];
    f[4*q+0] = v.x; f[4*q+1] = v.y; f[4*q+2] = v.z; f[4*q+3] = v.w;
    float4 u = agg4[(size_t)i * 16 + q];
    nv[4*q+0] = u.x; nv[4*q+1] = u.y; nv[4*q+2] = u.z; nv[4*q+3] = u.w;
  }

  const float4* A4 = (const float4*)sWsT;
  const float4* B4 = (const float4*)sWnT;
  float* orow = out + (size_t)i * 64;
  #pragma unroll 1
  for (int j = 0; j < 64; ++j) {
    float acc = sb[j];
    #pragma unroll
    for (int q = 0; q < 16; ++q) {
      float4 w = A4[j * 16 + q];
      acc += f[4*q+0]*w.x + f[4*q+1]*w.y + f[4*q+2]*w.z + f[4*q+3]*w.w;
      float4 u = B4[j * 16 + q];
      acc += nv[4*q+0]*u.x + nv[4*q+1]*u.y + nv[4*q+2]*u.z + nv[4*q+3]*u.w;
    }
    orow[j] = fmaxf(acc, 0.f);
  }
}

// ---------------- head precompute: za = h@W1[0:64], zb = h@W1[64:128] ----------------

__global__ __launch_bounds__(128) void k_zab(
    const float* __restrict__ hf, const float* __restrict__ W1,
    float* __restrict__ za, float* __restrict__ zb, int N)
{
  __shared__ float sAT[64 * 64];
  __shared__ float sBT[64 * 64];
  for (int idx = threadIdx.x; idx < 4096; idx += 128) {
    int k = idx >> 6, j = idx & 63;
    sAT[j * 64 + k] = W1[idx];
    sBT[j * 64 + k] = W1[4096 + idx];
  }
  __syncthreads();
  int i = blockIdx.x * 128 + threadIdx.x;
  if (i >= N) return;
  const float4* h4 = (const float4*)hf;
  float f[64];
  #pragma unroll
  for (int q = 0; q < 16; ++q) {
    float4 v = h4[(size_t)i * 16 + q];
    f[4*q+0] = v.x; f[4*q+1] = v.y; f[4*q+2] = v.z; f[4*q+3] = v.w;
  }
  const float4* A4 = (const float4*)sAT;
  const float4* B4 = (const float4*)sBT;
  float* zar = za + (size_t)i * 64;
  float* zbr = zb + (size_t)i * 64;
  #pragma unroll 1
  for (int j = 0; j < 64; ++j) {
    float aa = 0.f, bb = 0.f;
    #pragma unroll
    for (int q = 0; q < 16; ++q) {
      float4 w = A4[j * 16 + q];
      aa += f[4*q+0]*w.x + f[4*q+1]*w.y + f[4*q+2]*w.z + f[4*q+3]*w.w;
      float4 u = B4[j * 16 + q];
      bb += f[4*q+0]*u.x + f[4*q+1]*u.y + f[4*q+2]*u.z + f[4*q+3]*u.w;
    }
    zar[j] = aa; zbr[j] = bb;
  }
}

// ---------------- head: out = relu(za[x1]+zb[x2]+|h1-h2|@W1c + b1) @ W2 + b2 ----------------

__global__ __launch_bounds__(256) void k_head_z(
    const float* __restrict__ hf, const float* __restrict__ za, const float* __restrict__ zb,
    const int* __restrict__ x1, const int* __restrict__ x2,
    const float* __restrict__ W1, const float* __restrict__ bl1,
    const float* __restrict__ W2, const float* __restrict__ bl2,
    float* __restrict__ out, int P)
{
  __shared__ float sCT[64 * 64];
  __shared__ float sW2[128];
  __shared__ float sb1[64];
  __shared__ float sb2[2];
  for (int idx = threadIdx.x; idx < 4096; idx += 256) {
    int k = idx >> 6, j = idx & 63;
    sCT[j * 64 + k] = W1[8192 + idx];   // W1 rows 128..191, transposed
  }
  if (threadIdx.x < 128) sW2[threadIdx.x] = W2[threadIdx.x];
  if (threadIdx.x < 64)  sb1[threadIdx.x] = bl1[threadIdx.x];
  if (threadIdx.x < 2)   sb2[threadIdx.x] = bl2[threadIdx.x];
  __syncthreads();

  int p = blockIdx.x * 256 + threadIdx.x;
  if (p >= P) return;
  int i1 = x1[p], i2 = x2[p];
  const float4* h4 = (const float4*)hf;
  const float4* za4 = (const float4*)za;
  const float4* zb4 = (const float4*)zb;
  float a[64], zs[64];
  #pragma unroll
  for (int q = 0; q < 16; ++q) {
    float4 v1 = h4[(size_t)i1 * 16 + q];
    float4 v2 = h4[(size_t)i2 * 16 + q];
    a[4*q+0] = fabsf(v1.x - v2.x);
    a[4*q+1] = fabsf(v1.y - v2.y);
    a[4*q+2] = fabsf(v1.z - v2.z);
    a[4*q+3] = fabsf(v1.w - v2.w);
    float4 u1 = za4[(size_t)i1 * 16 + q];
    float4 u2 = zb4[(size_t)i2 * 16 + q];
    zs[4*q+0] = u1.x + u2.x;
    zs[4*q+1] = u1.y + u2.y;
    zs[4*q+2] = u1.z + u2.z;
    zs[4*q+3] = u1.w + u2.w;
  }
  const float4* C4 = (const float4*)sCT;
  float o0 = 0.f, o1 = 0.f;
  #pragma unroll
  for (int j = 0; j < 64; ++j) {
    float acc = sb1[j] + zs[j];
    #pragma unroll
    for (int q = 0; q < 16; ++q) {
      float4 w = C4[j * 16 + q];
      acc += a[4*q+0]*w.x + a[4*q+1]*w.y + a[4*q+2]*w.z + a[4*q+3]*w.w;
    }
    float r = fmaxf(acc, 0.f);
    o0 += r * sW2[2*j + 0];
    o1 += r * sW2[2*j + 1];
  }
  out[(size_t)p * 2 + 0] = o0 + sb2[0];
  out[(size_t)p * 2 + 1] = o1 + sb2[1];
}

// ---------------- launch ----------------

extern "C" void kernel_launch(void* const* d_in, const int* in_sizes, int n_in,
                              void* d_out, int out_size, void* d_ws, size_t ws_size,
                              hipStream_t stream)
{
  (void)n_in; (void)out_size; (void)ws_size;
  const float* h   = (const float*)d_in[0];
  const int*   src = (const int*)d_in[1];
  const int*   dst = (const int*)d_in[2];
  const int*   x1  = (const int*)d_in[3];
  const int*   x2  = (const int*)d_in[4];
  const float* Ws0 = (const float*)d_in[5];
  const float* Wn0 = (const float*)d_in[6];
  const float* b0  = (const float*)d_in[7];
  const float* Ws1 = (const float*)d_in[8];
  const float* Wn1 = (const float*)d_in[9];
  const float* b1  = (const float*)d_in[10];
  const float* W1  = (const float*)d_in[11];
  const float* bl1 = (const float*)d_in[12];
  const float* W2  = (const float*)d_in[13];
  const float* bl2 = (const float*)d_in[14];

  const int N = in_sizes[0] / 64;
  const int E = in_sizes[1];
  const int P = in_sizes[3];
  float* out = (float*)d_out;

  char* ws = (char*)d_ws;
  size_t off = 0;
  auto carve = [&](size_t bytes) {
    char* p = ws + off;
    off = (off + bytes + 255) & ~(size_t)255;
    return p;
  };
  int*   cnt     = (int*)carve((size_t)N * 4);
  int*   row_ptr = (int*)carve((size_t)(N + 1) * 4);
  int*   cursor  = (int*)carve((size_t)N * 4);
  int*   bsum    = (int*)carve(512);
  int*   boff    = (int*)carve(512);
  int*   csr_src = (int*)carve((size_t)E * 4);
  float* buf1    = (float*)carve((size_t)N * 64 * 4);
  float* buf2    = (float*)carve((size_t)N * 64 * 4);
  float* zbuf    = (float*)carve((size_t)N * 64 * 4);  // agg scratch, later zb
  float* aggb = zbuf;     // agg is dead before k_zab writes zb
  float* zb   = zbuf;
  float* za   = buf1;     // buf1 is free after layer-1 xform consumes it

  const int NB = (N + 1023) / 1024;

  hipMemsetAsync(cnt, 0, (size_t)N * 4, stream);
  k_count<<<(E + 255) / 256, 256, 0, stream>>>(dst, cnt, E);
  k_scan1<<<NB, 256, 0, stream>>>(cnt, bsum, N);
  k_scan2<<<1, 128, 0, stream>>>(bsum, boff, row_ptr, NB, N);
  k_scan3<<<NB, 256, 0, stream>>>(cnt, boff, row_ptr, N);
  hipMemcpyAsync(cursor, row_ptr, (size_t)N * 4, hipMemcpyDeviceToDevice, stream);
  k_fill<<<(E + 255) / 256, 256, 0, stream>>>(src, dst, cursor, csr_src, E);

  const int nbW = (N + 3) / 4;        // 4 node-waves per 256-thread block
  const int nbX = (N + 127) / 128;    // 128-thread xform blocks

  k_agg  <<<nbW, 256, 0, stream>>>(h, row_ptr, csr_src, aggb, N);
  k_xform<<<nbX, 128, 0, stream>>>(h, aggb, Ws0, Wn0, b0, buf1, N);
  k_agg  <<<nbW, 256, 0, stream>>>(buf1, row_ptr, csr_src, aggb, N);
  k_xform<<<nbX, 128, 0, stream>>>(buf1, aggb, Ws1, Wn1, b1, buf2, N);

  k_zab<<<nbX, 128, 0, stream>>>(buf2, W1, za, zb, N);
  const int nbP = (P + 255) / 256;
  k_head_z<<<nbP, 256, 0, stream>>>(buf2, za, zb, x1, x2, W1, bl1, W2, bl2, out, P);
}

// Round 3
// 539.022 us; speedup vs baseline: 1.7121x; 1.7121x over previous
//
#include <hip/hip_runtime.h>
#include <hip/hip_bf16.h>

using s8v = __attribute__((ext_vector_type(8))) short;   // 8 bf16 (4 VGPRs)
using f4v = __attribute__((ext_vector_type(4))) float;   // MFMA accumulator

__device__ __forceinline__ float bf2f(ushort v) { return __uint_as_float(((unsigned)v) << 16); }
__device__ __forceinline__ ushort f2bf(float x) {
  unsigned u = __float_as_uint(x);
  return (ushort)((u + 0x7fffu + ((u >> 16) & 1u)) >> 16);   // RNE, matches numpy
}

// ---------------- CSR build ----------------

__global__ void k_count(const int* __restrict__ dst, int* __restrict__ cnt, int E) {
  int e = blockIdx.x * 256 + threadIdx.x;
  if (e < E) atomicAdd(&cnt[dst[e]], 1);
}

__global__ void k_scan1(const int* __restrict__ cnt, int* __restrict__ bsum, int N) {
  __shared__ int sh[256];
  int t = threadIdx.x;
  int base = blockIdx.x * 1024 + t * 4;
  int s = 0;
  #pragma unroll
  for (int q = 0; q < 4; ++q) { int i = base + q; if (i < N) s += cnt[i]; }
  sh[t] = s; __syncthreads();
  for (int off = 128; off > 0; off >>= 1) {
    if (t < off) sh[t] += sh[t + off];
    __syncthreads();
  }
  if (t == 0) bsum[blockIdx.x] = sh[0];
}

__global__ void k_scan2(const int* __restrict__ bsum, int* __restrict__ boff,
                        int* __restrict__ row_ptr, int NB, int N) {
  __shared__ int sh[128];
  int t = threadIdx.x;
  int v = (t < NB) ? bsum[t] : 0;
  sh[t] = v; __syncthreads();
  for (int off = 1; off < 128; off <<= 1) {
    int y = (t >= off) ? sh[t - off] : 0;
    __syncthreads();
    sh[t] += y;
    __syncthreads();
  }
  if (t < NB) boff[t] = sh[t] - v;
  if (t == 127) row_ptr[N] = sh[127];
}

__global__ void k_scan3(const int* __restrict__ cnt, const int* __restrict__ boff,
                        int* __restrict__ row_ptr, int N) {
  __shared__ int sh[256];
  int t = threadIdx.x;
  int base = blockIdx.x * 1024 + t * 4;
  int c0 = 0, c1 = 0, c2 = 0, c3 = 0;
  if (base + 0 < N) c0 = cnt[base + 0];
  if (base + 1 < N) c1 = cnt[base + 1];
  if (base + 2 < N) c2 = cnt[base + 2];
  if (base + 3 < N) c3 = cnt[base + 3];
  int s = c0 + c1 + c2 + c3;
  sh[t] = s; __syncthreads();
  for (int off = 1; off < 256; off <<= 1) {
    int y = (t >= off) ? sh[t - off] : 0;
    __syncthreads();
    sh[t] += y;
    __syncthreads();
  }
  int run = boff[blockIdx.x] + sh[t] - s;
  if (base + 0 < N) row_ptr[base + 0] = run; run += c0;
  if (base + 1 < N) row_ptr[base + 1] = run; run += c1;
  if (base + 2 < N) row_ptr[base + 2] = run; run += c2;
  if (base + 3 < N) row_ptr[base + 3] = run;
}

__global__ void k_fill(const int* __restrict__ src, const int* __restrict__ dst,
                       int* __restrict__ cursor, int* __restrict__ csr_src, int E) {
  int e = blockIdx.x * 256 + threadIdx.x;
  if (e < E) {
    int pos = atomicAdd(&cursor[dst[e]], 1);
    csr_src[pos] = src[e];
  }
}

// ---------------- fp32 -> bf16 cast (8 elems/thread) ----------------

__global__ __launch_bounds__(256) void k_cast(const float* __restrict__ in,
                                              ushort* __restrict__ outb, int n8) {
  int i = blockIdx.x * 256 + threadIdx.x;
  if (i >= n8) return;
  const float4* in4 = (const float4*)in;
  float4 va = in4[2 * i], vb = in4[2 * i + 1];
  s8v w;
  w[0] = (short)f2bf(va.x); w[1] = (short)f2bf(va.y);
  w[2] = (short)f2bf(va.z); w[3] = (short)f2bf(va.w);
  w[4] = (short)f2bf(vb.x); w[5] = (short)f2bf(vb.y);
  w[6] = (short)f2bf(vb.z); w[7] = (short)f2bf(vb.w);
  ((s8v*)outb)[i] = w;
}

// ---------------- aggregation: wave-per-node, 4 edges per wave-load ----------------
// lane = 16*g + c; group g handles edge e+g, lane covers bf16 columns 4c..4c+3.
// One wave load = 4 edges x 8B x 16 lanes = 8 cache lines in flight.

__global__ __launch_bounds__(256) void k_agg_bf(
    const ushort* __restrict__ fb, const int* __restrict__ rp,
    const int* __restrict__ csrc, float* __restrict__ agg, int N)
{
  int lane = threadIdx.x & 63;
  int node = (blockIdx.x * 256 + threadIdx.x) >> 6;
  if (node >= N) return;
  int g  = lane >> 4;
  int c4 = (lane & 15) * 4;
  int e0 = rp[node], e1 = rp[node + 1];
  float a0 = 0.f, a1 = 0.f, a2 = 0.f, a3 = 0.f;
  for (int e = e0; e < e1; e += 4) {
    int ee = e + g;
    if (ee < e1) {
      int s = csrc[ee];
      ushort4 v = *(const ushort4*)(fb + (size_t)s * 64 + c4);
      a0 += bf2f(v.x); a1 += bf2f(v.y); a2 += bf2f(v.z); a3 += bf2f(v.w);
    }
  }
  a0 += __shfl_xor(a0, 16); a0 += __shfl_xor(a0, 32);
  a1 += __shfl_xor(a1, 16); a1 += __shfl_xor(a1, 32);
  a2 += __shfl_xor(a2, 16); a2 += __shfl_xor(a2, 32);
  a3 += __shfl_xor(a3, 16); a3 += __shfl_xor(a3, 32);
  int len = e1 - e0;
  float inv = 1.f / (float)(len > 0 ? len : 1);
  if (g == 0) {
    float4 o = make_float4(a0 * inv, a1 * inv, a2 * inv, a3 * inv);
    *(float4*)(agg + (size_t)node * 64 + c4) = o;
  }
}

// ---------------- transform: out = relu(f@Ws + agg@Wn + b); writes bf16 (+opt fp32) ----------------

__global__ __launch_bounds__(128) void k_xform(
    const float* __restrict__ feat, const float* __restrict__ agg,
    const float* __restrict__ Ws, const float* __restrict__ Wn,
    const float* __restrict__ bias, float* __restrict__ out32,
    ushort* __restrict__ outb, int N, int write32)
{
  __shared__ float sWsT[64 * 64];
  __shared__ float sWnT[64 * 64];
  __shared__ float sb[64];
  for (int idx = threadIdx.x; idx < 4096; idx += 128) {
    int k = idx >> 6, j = idx & 63;
    sWsT[j * 64 + k] = Ws[idx];
    sWnT[j * 64 + k] = Wn[idx];
  }
  if (threadIdx.x < 64) sb[threadIdx.x] = bias[threadIdx.x];
  __syncthreads();

  int i = blockIdx.x * 128 + threadIdx.x;
  if (i >= N) return;

  const float4* feat4 = (const float4*)feat;
  const float4* agg4  = (const float4*)agg;
  float f[64], nv[64];
  #pragma unroll
  for (int q = 0; q < 16; ++q) {
    float4 v = feat4[(size_t)i * 16 + q];
    f[4*q+0] = v.x; f[4*q+1] = v.y; f[4*q+2] = v.z; f[4*q+3] = v.w;
    float4 u = agg4[(size_t)i * 16 + q];
    nv[4*q+0] = u.x; nv[4*q+1] = u.y; nv[4*q+2] = u.z; nv[4*q+3] = u.w;
  }

  const float4* A4 = (const float4*)sWsT;
  const float4* B4 = (const float4*)sWnT;
  float* orow = out32 + (size_t)i * 64;
  ushort* brow = outb + (size_t)i * 64;
  #pragma unroll 1
  for (int jo = 0; jo < 8; ++jo) {
    float rr[8];
    #pragma unroll
    for (int jj = 0; jj < 8; ++jj) {
      int j = jo * 8 + jj;
      float acc = sb[j];
      #pragma unroll
      for (int q = 0; q < 16; ++q) {
        float4 w = A4[j * 16 + q];
        acc += f[4*q+0]*w.x + f[4*q+1]*w.y + f[4*q+2]*w.z + f[4*q+3]*w.w;
        float4 u = B4[j * 16 + q];
        acc += nv[4*q+0]*u.x + nv[4*q+1]*u.y + nv[4*q+2]*u.z + nv[4*q+3]*u.w;
      }
      rr[jj] = fmaxf(acc, 0.f);
    }
    if (write32) {
      float4 o0 = make_float4(rr[0], rr[1], rr[2], rr[3]);
      float4 o1 = make_float4(rr[4], rr[5], rr[6], rr[7]);
      *(float4*)(orow + jo * 8 + 0) = o0;
      *(float4*)(orow + jo * 8 + 4) = o1;
    }
    s8v pk;
    #pragma unroll
    for (int jj = 0; jj < 8; ++jj) pk[jj] = (short)f2bf(rr[jj]);
    *(s8v*)(brow + jo * 8) = pk;
  }
}

// ---------------- W1 -> transposed bf16, padded rows of 200 ----------------
// w1t[n*200 + k] = bf16(W1[k][n]), k<192; pad zeros.

__global__ __launch_bounds__(256) void k_prep_w1t(const float* __restrict__ W1,
                                                  ushort* __restrict__ w1t) {
  int idx = blockIdx.x * 256 + threadIdx.x;
  if (idx >= 64 * 200) return;
  int n = idx / 200, k = idx % 200;
  float v = (k < 192) ? W1[k * 64 + n] : 0.f;
  w1t[idx] = f2bf(v);
}

// ---------------- head via MFMA ----------------
// Per wave: 64 pairs. C(64x64) = h1*W1a + h2*W1b + |h1-h2|*W1c, then
// relu(+b1) @ W2 (64x2) via in-register reduce. A-fragments load DIRECTLY
// from global bf16 h: lanes {p,p+16,p+32,p+48} read contiguous 64B of row p
// -> every gather is one full cache line. W1^T bf16 staged in LDS (pad 200).

__global__ __launch_bounds__(256) void k_head_mfma(
    const ushort* __restrict__ hb, const int* __restrict__ x1, const int* __restrict__ x2,
    const ushort* __restrict__ w1t, const float* __restrict__ bl1,
    const float* __restrict__ W2, const float* __restrict__ bl2,
    float* __restrict__ out, int P)
{
  __shared__ __align__(16) ushort sW[64 * 200];
  __shared__ float sW2[128];
  __shared__ float sb1[64];
  __shared__ float sb2[2];
  {
    const float4* srcv = (const float4*)w1t;   // 12800 ushort = 1600 float4
    float4* dstv = (float4*)sW;
    for (int i = threadIdx.x; i < 1600; i += 256) dstv[i] = srcv[i];
    if (threadIdx.x < 128) sW2[threadIdx.x] = W2[threadIdx.x];
    if (threadIdx.x < 64)  sb1[threadIdx.x] = bl1[threadIdx.x];
    if (threadIdx.x < 2)   sb2[threadIdx.x] = bl2[threadIdx.x];
  }
  __syncthreads();

  int lane = threadIdx.x & 63;
  int wid  = threadIdx.x >> 6;
  int wbase = blockIdx.x * 256 + wid * 64;
  if (wbase >= P) return;

  int lrow = lane & 15;   // A row within 16-tile / C col within 16-tile
  int lkg  = lane >> 4;   // k-group (8 consecutive k)

  f4v acc[4][4];
  #pragma unroll
  for (int a = 0; a < 4; ++a)
    #pragma unroll
    for (int b = 0; b < 4; ++b)
      acc[a][b] = (f4v){0.f, 0.f, 0.f, 0.f};

  #pragma unroll 1
  for (int pt = 0; pt < 4; ++pt) {
    int p = wbase + pt * 16 + lrow;
    int pc = (p < P) ? p : (P - 1);
    int i1 = x1[pc], i2 = x2[pc];
    const ushort* r1 = hb + (size_t)i1 * 64;
    const ushort* r2 = hb + (size_t)i2 * 64;
    s8v a1[2], a2[2], a3[2];
    #pragma unroll
    for (int ks = 0; ks < 2; ++ks) {
      int ko = ks * 32 + lkg * 8;
      a1[ks] = *(const s8v*)(r1 + ko);
      a2[ks] = *(const s8v*)(r2 + ko);
      s8v d;
      #pragma unroll
      for (int j = 0; j < 8; ++j) {
        float fa = bf2f((ushort)a1[ks][j]);
        float fb = bf2f((ushort)a2[ks][j]);
        d[j] = (short)f2bf(fabsf(fa - fb));
      }
      a3[ks] = d;
    }
    #pragma unroll
    for (int nt = 0; nt < 4; ++nt) {
      int n = nt * 16 + lrow;
      const ushort* bw = &sW[n * 200 + lkg * 8];
      #pragma unroll
      for (int ks = 0; ks < 2; ++ks) {
        s8v b1f = *(const s8v*)(bw + ks * 32 + 0);
        s8v b2f = *(const s8v*)(bw + ks * 32 + 64);
        s8v b3f = *(const s8v*)(bw + ks * 32 + 128);
        acc[pt][nt] = __builtin_amdgcn_mfma_f32_16x16x32_bf16(a1[ks], b1f, acc[pt][nt], 0, 0, 0);
        acc[pt][nt] = __builtin_amdgcn_mfma_f32_16x16x32_bf16(a2[ks], b2f, acc[pt][nt], 0, 0, 0);
        acc[pt][nt] = __builtin_amdgcn_mfma_f32_16x16x32_bf16(a3[ks], b3f, acc[pt][nt], 0, 0, 0);
      }
    }
  }

  // epilogue: lane holds col n = nt*16+lrow, rows (lkg*4 + r) within each pt tile
  float b1v[4], w20v[4], w21v[4];
  #pragma unroll
  for (int nt = 0; nt < 4; ++nt) {
    int n = nt * 16 + lrow;
    b1v[nt] = sb1[n];
    w20v[nt] = sW2[2 * n + 0];
    w21v[nt] = sW2[2 * n + 1];
  }
  float bb0 = sb2[0], bb1 = sb2[1];
  #pragma unroll
  for (int pt = 0; pt < 4; ++pt) {
    #pragma unroll
    for (int r = 0; r < 4; ++r) {
      float p0 = 0.f, p1 = 0.f;
      #pragma unroll
      for (int nt = 0; nt < 4; ++nt) {
        float z = fmaxf(acc[pt][nt][r] + b1v[nt], 0.f);
        p0 += z * w20v[nt];
        p1 += z * w21v[nt];
      }
      p0 += __shfl_xor(p0, 1); p1 += __shfl_xor(p1, 1);
      p0 += __shfl_xor(p0, 2); p1 += __shfl_xor(p1, 2);
      p0 += __shfl_xor(p0, 4); p1 += __shfl_xor(p1, 4);
      p0 += __shfl_xor(p0, 8); p1 += __shfl_xor(p1, 8);
      int pair = wbase + pt * 16 + lkg * 4 + r;
      if (lrow == 0 && pair < P) {
        float2 o = make_float2(p0 + bb0, p1 + bb1);
        *(float2*)(out + 2 * (size_t)pair) = o;
      }
    }
  }
}

// ---------------- launch ----------------

extern "C" void kernel_launch(void* const* d_in, const int* in_sizes, int n_in,
                              void* d_out, int out_size, void* d_ws, size_t ws_size,
                              hipStream_t stream)
{
  (void)n_in; (void)out_size; (void)ws_size;
  const float* h   = (const float*)d_in[0];
  const int*   src = (const int*)d_in[1];
  const int*   dst = (const int*)d_in[2];
  const int*   x1  = (const int*)d_in[3];
  const int*   x2  = (const int*)d_in[4];
  const float* Ws0 = (const float*)d_in[5];
  const float* Wn0 = (const float*)d_in[6];
  const float* b0  = (const float*)d_in[7];
  const float* Ws1 = (const float*)d_in[8];
  const float* Wn1 = (const float*)d_in[9];
  const float* b1  = (const float*)d_in[10];
  const float* W1  = (const float*)d_in[11];
  const float* bl1 = (const float*)d_in[12];
  const float* W2  = (const float*)d_in[13];
  const float* bl2 = (const float*)d_in[14];

  const int N = in_sizes[0] / 64;
  const int E = in_sizes[1];
  const int P = in_sizes[3];
  float* out = (float*)d_out;

  char* ws = (char*)d_ws;
  size_t off = 0;
  auto carve = [&](size_t bytes) {
    char* p = ws + off;
    off = (off + bytes + 255) & ~(size_t)255;
    return p;
  };
  int*    cnt     = (int*)carve((size_t)N * 4);
  int*    row_ptr = (int*)carve((size_t)(N + 1) * 4);
  int*    cursor  = (int*)carve((size_t)N * 4);
  int*    bsum    = (int*)carve(512);
  int*    boff    = (int*)carve(512);
  int*    csr_src = (int*)carve((size_t)E * 4);
  ushort* h_bf    = (ushort*)carve((size_t)N * 64 * 2);
  ushort* m1      = (ushort*)carve((size_t)N * 64 * 2);
  ushort* m2      = (ushort*)carve((size_t)N * 64 * 2);
  float*  buf1    = (float*)carve((size_t)N * 64 * 4);
  float*  aggf    = (float*)carve((size_t)N * 64 * 4);
  ushort* w1t     = (ushort*)carve(64 * 200 * 2);

  const int NB = (N + 1023) / 1024;

  hipMemsetAsync(cnt, 0, (size_t)N * 4, stream);
  k_count<<<(E + 255) / 256, 256, 0, stream>>>(dst, cnt, E);
  k_scan1<<<NB, 256, 0, stream>>>(cnt, bsum, N);
  k_scan2<<<1, 128, 0, stream>>>(bsum, boff, row_ptr, NB, N);
  k_scan3<<<NB, 256, 0, stream>>>(cnt, boff, row_ptr, N);
  hipMemcpyAsync(cursor, row_ptr, (size_t)N * 4, hipMemcpyDeviceToDevice, stream);
  k_fill<<<(E + 255) / 256, 256, 0, stream>>>(src, dst, cursor, csr_src, E);

  k_cast<<<(N * 64 / 8 + 255) / 256, 256, 0, stream>>>(h, h_bf, N * 64 / 8);
  k_prep_w1t<<<(64 * 200 + 255) / 256, 256, 0, stream>>>(W1, w1t);

  const int nbW = (N + 3) / 4;       // wave-per-node agg
  const int nbX = (N + 127) / 128;   // xform

  k_agg_bf<<<nbW, 256, 0, stream>>>(h_bf, row_ptr, csr_src, aggf, N);
  k_xform<<<nbX, 128, 0, stream>>>(h, aggf, Ws0, Wn0, b0, buf1, m1, N, 1);
  k_agg_bf<<<nbW, 256, 0, stream>>>(m1, row_ptr, csr_src, aggf, N);
  k_xform<<<nbX, 128, 0, stream>>>(buf1, aggf, Ws1, Wn1, b1, buf1, m2, N, 0);

  const int nbP = (P + 255) / 256;
  k_head_mfma<<<nbP, 256, 0, stream>>>(m2, x1, x2, w1t, bl1, W2, bl2, out, P);
}